// Round 12
// baseline (55.162 us; speedup 1.0000x reference)
//
#include <hip/hip_runtime.h>

#define Tn 512
#define Bn 2048
#define Dn 2
#define NQn 4

#define INV2PI 0.15915494309189535f   // 1/(2*pi)
#define L2E    1.4426950408889634f    // log2(e)

__device__ __forceinline__ float fsig_hw(float x) {
    return __builtin_amdgcn_rcpf(1.f + __builtin_amdgcn_exp2f(-x * L2E));
}
// full-rate DPP permute; CTRL 0x00-0xFF = quad_perm, 0x121-0x12F = row_ror
template<int CTRL>
__device__ __forceinline__ float dppf(float x) {
    return __int_as_float(__builtin_amdgcn_mov_dpp(__float_as_int(x), CTRL, 0xF, 0xF, true));
}

__launch_bounds__(256)
__global__ void fraud_lstm_kernel(
    const float* __restrict__ seq,
    const float* __restrict__ Wf, const float* __restrict__ bf, const float* __restrict__ pf,
    const float* __restrict__ Wi, const float* __restrict__ bi, const float* __restrict__ pi,
    const float* __restrict__ Wu, const float* __restrict__ bu, const float* __restrict__ pu,
    const float* __restrict__ Wo, const float* __restrict__ bo, const float* __restrict__ po,
    const float* __restrict__ Wc, const float* __restrict__ bc,
    float* __restrict__ out)
{
    __shared__ float swArr[12], w0s[12], w1s[12], kqs[12];
    __shared__ float W0c[16], W1c[16], kqc[16];   // sign-combined column weights
    __shared__ float2 xs[Tn];
    __shared__ float zbuf[(Tn + 18) * 16];  // cos-sum bases, 16 cols = (gate, combo); rows >=512 zeroed
    __shared__ float hbufx[Tn + 80];        // h per step (lane0) + dump area
    __shared__ float sumWc;

    const int tid = threadIdx.x;
    const int lane = tid & 63;
    const int wav = tid >> 6;
    const float* Wg[4] = {Wf, Wi, Wu, Wo};
    const float* bg[4] = {bf, bi, bu, bo};
    const float* pg[4] = {pf, pi, pu, po};

    // ---- stage x[t] = seq[t, B-1, 0:2] into LDS (256 threads -> 2 rounds) ----
    for (int t = tid; t < Tn; t += 256) {
        const float* p = seq + (size_t)t * (Bn * Dn) + (size_t)(Bn - 1) * Dn;
        xs[t] = make_float2(p[0], p[1]);
    }

    // ---- reduce weights, split across waves: wave w owns m = 3w..3w+2; wave 3 also Wc ----
    #pragma unroll
    for (int mi = 0; mi < 3; ++mi) {
        const int m = wav * 3 + mi;
        const int g = m / 3, q = 1 + (m % 3);
        float v = Wg[g][(Dn + lane) * NQn + q];
        #pragma unroll
        for (int off = 32; off > 0; off >>= 1) v += __shfl_down(v, off, 64);
        if (lane == 0) {
            swArr[m] = v * INV2PI;
            w0s[m]   = Wg[g][0 * NQn + q];
            w1s[m]   = Wg[g][1 * NQn + q];
            kqs[m]   = bg[g][q] + pg[g][q];
        }
    }
    if (wav == 3) {
        float v = Wc[lane];
        #pragma unroll
        for (int off = 32; off > 0; off >>= 1) v += __shfl_down(v, off, 64);
        if (lane == 0) sumWc = v;
    }
    __syncthreads();

    // ---- sign-combined column weights: col = 2*l8 + ab (g = l8&3, s2 = l8>>2) ----
    // combos: (s2,ab)=(0,0):+++  (0,1):++-  (1,0):+-+  (1,1):-++
    if (tid < 16) {
        const int col = tid, l8 = col >> 1, ab = col & 1;
        const int g = l8 & 3, s2 = l8 >> 2;
        const float sg0 = (s2 == 1 && ab == 1) ? -1.f : 1.f;
        const float sg1 = (s2 == 1 && ab == 0) ? -1.f : 1.f;
        const float sg2 = (s2 == 0 && ab == 1) ? -1.f : 1.f;
        const int m = g * 3;
        W0c[col] = sg0 * w0s[m] + sg1 * w0s[m + 1] + sg2 * w0s[m + 2];
        W1c[col] = sg0 * w1s[m] + sg1 * w1s[m + 1] + sg2 * w1s[m + 2];
        kqc[col] = sg0 * kqs[m] + sg1 * kqs[m + 1] + sg2 * kqs[m + 2];
    }
    __syncthreads();

    // ---- parallel precompute zbuf: B_col(t) = (x.W0c + x2.W1c + kqc)/2pi (256 thr -> 32 iters) ----
    {
        const int col = tid & 15;
        const float w0 = W0c[col], w1 = W1c[col], kq = kqc[col];
        for (int t0 = (tid >> 4); t0 < Tn; t0 += 16) {
            const float2 x = xs[t0];
            zbuf[t0 * 16 + col] = fmaf(x.x, w0, fmaf(x.y, w1, kq)) * INV2PI;
        }
        for (int i = tid; i < 18 * 16; i += 256) zbuf[Tn * 16 + i] = 0.f;  // rows 512..529
    }
    __syncthreads();

    // ---- serial recurrence on wave 0 only; waves 1-3 sleep at the barrier ----
    // pre_g = (1/4) sum of 4 cos (product-to-sum identity); lane l8: gate g=l8&3, pair s2=l8>>2.
    // 4-sum completed by ONE row_ror:4 dpp-add (8-periodic redundancy -> direction-immune).
    // Gate: [3/3] Pade in w = s^2 (scales folded), reciprocal via quadratic Cheb seed + 1 Newton.
    // Cell tanh [3/3]; 1/Q2 via quadratic Cheb seed + 2 Newton (NO trans op on the tail).
    if (tid < 64) {
        const int l8 = tid & 7;
        const int g  = l8 & 3;
        const int s2 = l8 >> 2;
        const bool isG2 = (g == 2);
        const int m = g * 3;
        const float sw0 = swArr[m], sw1 = swArr[m + 1], sw2 = swArr[m + 2];
        const float WAc = s2 ? (sw0 - sw1 + sw2) : (sw0 + sw1 + sw2);
        const float WBc = s2 ? (-sw0 + sw1 + sw2) : (sw0 + sw1 - sw2);
        // gate Pade coeffs on w = s^2 in [0,16]  (A = s*Pn(w)/Qd(w) + addA)
        const float cp0 = 236.25f;                                  // 945/4 (both)
        const float cp1 = isG2 ? 1.640625f       : 0.41015625f;     // /64
        const float cp2 = isG2 ? 9.765625e-4f    : 6.1035156e-5f;   // /1024
        const float cq0 = isG2 ? 945.f           : 3780.f;
        const float cq1 = 26.25f;                                   // 420/16 (both)
        const float cq2 = isG2 ? 5.859375e-2f    : 1.46484375e-2f;  // /256
        const float addA = isG2 ? 0.f : 0.5f;
        // reciprocal seed for 1/Qd on w in [0,16]
        const float NA = isG2 ? 4.41153125e-7f  : 1.01330586e-8f;
        const float NB = isG2 ? -2.77550938e-5f : -1.82661500e-6f;
        const float NC = isG2 ? 1.056778e-3f    : 2.645420e-4f;
        // cell 1/Q2 quadratic Cheb seed on y in [0,4.5] (max rel err ~4.5%; 2 Newtons -> ~4e-6)
        const float CA = 9.26351e-5f;
        const float CB = -2.79870e-5f;
        const float CC = 3.0788e-6f;

        const float2* zb2p = (const float2*)zbuf;
        float c = 0.f;
        float2 z0 = zb2p[l8];           // row 0
        float zaccA = z0.x, zaccB = z0.y;   // z(0) = base(0) since h(-1)=0
        float2 za2[16], zb2[16];
        #pragma unroll
        for (int k = 0; k < 16; ++k) za2[k] = zb2p[(k + 1) * 8 + l8];   // rows 1..16
        int ldoff = 17 * 8 + l8;        // next burst: rows 17..32 (float2 units)
        int hidx  = (tid == 0) ? 0 : (Tn + 1 + tid);
        const int hstep = (tid == 0) ? 1 : 0;

#define STEP(ZN2)                                                            \
        {                                                                    \
            const float cA = __builtin_amdgcn_cosf(zaccA);                   \
            const float cB = __builtin_amdgcn_cosf(zaccB);                   \
            const float sP = cA + cB;                                        \
            const float s  = sP + dppf<0x124>(sP);                           \
            const float w2 = s * s;                                          \
            const float Qd = fmaf(w2, fmaf(w2, cq2, cq1), cq0);              \
            const float r0 = fmaf(w2, fmaf(w2, NA, NB), NC);                 \
            const float Pn = fmaf(w2, fmaf(w2, cp2, cp1), cp0);              \
            const float uPr = (s * Pn) * r0;                                 \
            const float m1 = Qd * r0;                                        \
            const float A  = fmaf(uPr, (2.f - m1), addA);                    \
            const float fg = dppf<0x00>(A);                                  \
            const float ig = dppf<0x55>(A);                                  \
            const float gu = dppf<0xAA>(A);                                  \
            const float og = dppf<0xFF>(A);                                  \
            c = fmaf(fg, c, ig * gu);                                        \
            const float y   = c * c;                                         \
            const float Q2  = fmaf(y, fmaf(y, (y + 210.f), 4725.f), 10395.f);\
            const float r0c = fmaf(y, fmaf(y, CC, CB), CA);                  \
            const float t0c = r0c + r0c;                                     \
            const float m1c = Q2 * r0c;                                      \
            const float r1c = fmaf(-r0c, m1c, t0c);                          \
            const float t1c = r1c + r1c;                                     \
            const float m2c = Q2 * r1c;                                      \
            const float rQ2 = fmaf(-r1c, m2c, t1c);                          \
            const float P2 = fmaf(y, fmaf(y, 21.f, 1260.f), 10395.f);        \
            const float ocP = (og * c) * P2;                                 \
            const float kA = ocP * WAc;                                      \
            const float kB = ocP * WBc;                                      \
            zaccA = fmaf(kA, rQ2, (ZN2).x);                                  \
            zaccB = fmaf(kB, rQ2, (ZN2).y);                                  \
            hbufx[hidx] = ocP * rQ2;                                         \
            hidx += hstep;                                                   \
        }

        for (int sbp = 0; sbp < 16; ++sbp) {
            #pragma unroll
            for (int k = 0; k < 16; ++k) zb2[k] = zb2p[ldoff + k * 8];
            #pragma unroll
            for (int k = 0; k < 16; ++k) STEP(za2[k]);
            ldoff += 128;
            #pragma unroll
            for (int k = 0; k < 16; ++k) za2[k] = zb2p[ldoff + k * 8];
            #pragma unroll
            for (int k = 0; k < 16; ++k) STEP(zb2[k]);
            ldoff += 128;
        }
#undef STEP
    }
    __syncthreads();

    // ---- epilogue: out[t] = sigmoid(h[t]*sum(Wc) + bc) (256 threads -> 2 iters) ----
    const float swc = sumWc, b0 = bc[0];
    for (int t = tid; t < Tn; t += 256) {
        out[t] = fsig_hw(fmaf(hbufx[t], swc, b0));
    }
}

extern "C" void kernel_launch(void* const* d_in, const int* in_sizes, int n_in,
                              void* d_out, int out_size, void* d_ws, size_t ws_size,
                              hipStream_t stream) {
    const float* seq = (const float*)d_in[0];
    const float* Wf  = (const float*)d_in[1];
    const float* bf  = (const float*)d_in[2];
    const float* pf  = (const float*)d_in[3];
    const float* Wi  = (const float*)d_in[4];
    const float* bi  = (const float*)d_in[5];
    const float* pi  = (const float*)d_in[6];
    const float* Wu  = (const float*)d_in[7];
    const float* bu  = (const float*)d_in[8];
    const float* pu  = (const float*)d_in[9];
    const float* Wo  = (const float*)d_in[10];
    const float* bo  = (const float*)d_in[11];
    const float* po  = (const float*)d_in[12];
    const float* Wc  = (const float*)d_in[13];
    const float* bc  = (const float*)d_in[14];
    float* out = (float*)d_out;

    fraud_lstm_kernel<<<1, 256, 0, stream>>>(seq, Wf, bf, pf, Wi, bi, pi,
                                             Wu, bu, pu, Wo, bo, po, Wc, bc, out);
}

// Round 13
// 50.021 us; speedup vs baseline: 1.1028x; 1.1028x over previous
//
#include <hip/hip_runtime.h>

#define Tn 512
#define Bn 2048
#define Dn 2
#define NQn 4

#define INV2PI 0.15915494309189535f   // 1/(2*pi)
#define L2E    1.4426950408889634f    // log2(e)

__device__ __forceinline__ float fsig_hw(float x) {
    return __builtin_amdgcn_rcpf(1.f + __builtin_amdgcn_exp2f(-x * L2E));
}
// full-rate DPP permute; CTRL 0x00-0xFF = quad_perm, 0x121-0x12F = row_ror
template<int CTRL>
__device__ __forceinline__ float dppf(float x) {
    return __int_as_float(__builtin_amdgcn_mov_dpp(__float_as_int(x), CTRL, 0xF, 0xF, true));
}

__launch_bounds__(256)
__global__ void fraud_lstm_kernel(
    const float* __restrict__ seq,
    const float* __restrict__ Wf, const float* __restrict__ bf, const float* __restrict__ pf,
    const float* __restrict__ Wi, const float* __restrict__ bi, const float* __restrict__ pi,
    const float* __restrict__ Wu, const float* __restrict__ bu, const float* __restrict__ pu,
    const float* __restrict__ Wo, const float* __restrict__ bo, const float* __restrict__ po,
    const float* __restrict__ Wc, const float* __restrict__ bc,
    float* __restrict__ out)
{
    __shared__ float swArr[12], w0s[12], w1s[12], kqs[12];
    __shared__ float W0c[16], W1c[16], kqc[16];   // sign-combined column weights
    __shared__ float2 xs[Tn];
    __shared__ float zbuf[(Tn + 18) * 16];  // cos-sum bases, 16 cols = (gate, combo); rows >=512 zeroed
    __shared__ float hbufx[Tn + 80];        // h per step (lane0) + dump area
    __shared__ float sumWc;

    const int tid = threadIdx.x;
    const int lane = tid & 63;
    const int wav = tid >> 6;
    const float* Wg[4] = {Wf, Wi, Wu, Wo};
    const float* bg[4] = {bf, bi, bu, bo};
    const float* pg[4] = {pf, pi, pu, po};

    // ---- stage x[t] = seq[t, B-1, 0:2] into LDS (256 threads -> 2 rounds) ----
    for (int t = tid; t < Tn; t += 256) {
        const float* p = seq + (size_t)t * (Bn * Dn) + (size_t)(Bn - 1) * Dn;
        xs[t] = make_float2(p[0], p[1]);
    }

    // ---- reduce weights, split across waves: wave w owns m = 3w..3w+2; wave 3 also Wc ----
    #pragma unroll
    for (int mi = 0; mi < 3; ++mi) {
        const int m = wav * 3 + mi;
        const int g = m / 3, q = 1 + (m % 3);
        float v = Wg[g][(Dn + lane) * NQn + q];
        #pragma unroll
        for (int off = 32; off > 0; off >>= 1) v += __shfl_down(v, off, 64);
        if (lane == 0) {
            swArr[m] = v * INV2PI;
            w0s[m]   = Wg[g][0 * NQn + q];
            w1s[m]   = Wg[g][1 * NQn + q];
            kqs[m]   = bg[g][q] + pg[g][q];
        }
    }
    if (wav == 3) {
        float v = Wc[lane];
        #pragma unroll
        for (int off = 32; off > 0; off >>= 1) v += __shfl_down(v, off, 64);
        if (lane == 0) sumWc = v;
    }
    __syncthreads();

    // ---- sign-combined column weights: col = 2*l8 + ab (g = l8&3, s2 = l8>>2) ----
    // combos: (s2,ab)=(0,0):+++  (0,1):++-  (1,0):+-+  (1,1):-++
    if (tid < 16) {
        const int col = tid, l8 = col >> 1, ab = col & 1;
        const int g = l8 & 3, s2 = l8 >> 2;
        const float sg0 = (s2 == 1 && ab == 1) ? -1.f : 1.f;
        const float sg1 = (s2 == 1 && ab == 0) ? -1.f : 1.f;
        const float sg2 = (s2 == 0 && ab == 1) ? -1.f : 1.f;
        const int m = g * 3;
        W0c[col] = sg0 * w0s[m] + sg1 * w0s[m + 1] + sg2 * w0s[m + 2];
        W1c[col] = sg0 * w1s[m] + sg1 * w1s[m + 1] + sg2 * w1s[m + 2];
        kqc[col] = sg0 * kqs[m] + sg1 * kqs[m + 1] + sg2 * kqs[m + 2];
    }
    __syncthreads();

    // ---- parallel precompute zbuf: B_col(t) = (x.W0c + x2.W1c + kqc)/2pi (256 thr -> 32 iters) ----
    {
        const int col = tid & 15;
        const float w0 = W0c[col], w1 = W1c[col], kq = kqc[col];
        for (int t0 = (tid >> 4); t0 < Tn; t0 += 16) {
            const float2 x = xs[t0];
            zbuf[t0 * 16 + col] = fmaf(x.x, w0, fmaf(x.y, w1, kq)) * INV2PI;
        }
        for (int i = tid; i < 18 * 16; i += 256) zbuf[Tn * 16 + i] = 0.f;  // rows 512..529
    }
    __syncthreads();

    // ---- serial recurrence on wave 0 only; waves 1-3 sleep at the barrier ----
    // pre_g = (1/4) sum of 4 cos (product-to-sum identity); lane l8: gate g=l8&3, pair s2=l8>>2.
    // 4-sum completed by ONE row_ror:4 dpp-add (8-periodic redundancy -> direction-immune).
    // Gate: [3/3] Pade in w = s^2 (scales folded), reciprocal via quadratic Cheb seed + 1 Newton.
    // Cell tanh [3/3] + v_rcp (R12 measured: v_rcp dep-latency ~22 cyc < 2-Newton chain ~44).
    if (tid < 64) {
        const int l8 = tid & 7;
        const int g  = l8 & 3;
        const int s2 = l8 >> 2;
        const bool isG2 = (g == 2);
        const int m = g * 3;
        const float sw0 = swArr[m], sw1 = swArr[m + 1], sw2 = swArr[m + 2];
        const float WAc = s2 ? (sw0 - sw1 + sw2) : (sw0 + sw1 + sw2);
        const float WBc = s2 ? (-sw0 + sw1 + sw2) : (sw0 + sw1 - sw2);
        // gate Pade coeffs on w = s^2 in [0,16]  (A = s*Pn(w)/Qd(w) + addA)
        const float cp0 = 236.25f;                                  // 945/4 (both)
        const float cp1 = isG2 ? 1.640625f       : 0.41015625f;     // /64
        const float cp2 = isG2 ? 9.765625e-4f    : 6.1035156e-5f;   // /1024
        const float cq0 = isG2 ? 945.f           : 3780.f;
        const float cq1 = 26.25f;                                   // 420/16 (both)
        const float cq2 = isG2 ? 5.859375e-2f    : 1.46484375e-2f;  // /256
        const float addA = isG2 ? 0.f : 0.5f;
        // reciprocal seed for 1/Qd on w in [0,16]
        const float NA = isG2 ? 4.41153125e-7f  : 1.01330586e-8f;
        const float NB = isG2 ? -2.77550938e-5f : -1.82661500e-6f;
        const float NC = isG2 ? 1.056778e-3f    : 2.645420e-4f;

        const float2* zb2p = (const float2*)zbuf;
        float c = 0.f;
        float2 z0 = zb2p[l8];           // row 0
        float zaccA = z0.x, zaccB = z0.y;   // z(0) = base(0) since h(-1)=0
        float2 za2[16], zb2[16];
        #pragma unroll
        for (int k = 0; k < 16; ++k) za2[k] = zb2p[(k + 1) * 8 + l8];   // rows 1..16
        int ldoff = 17 * 8 + l8;        // next burst: rows 17..32 (float2 units)
        int hidx  = (tid == 0) ? 0 : (Tn + 1 + tid);
        const int hstep = (tid == 0) ? 1 : 0;

#define STEP(ZN2)                                                            \
        {                                                                    \
            const float cA = __builtin_amdgcn_cosf(zaccA);                   \
            const float cB = __builtin_amdgcn_cosf(zaccB);                   \
            const float sP = cA + cB;                                        \
            const float s  = sP + dppf<0x124>(sP);                           \
            const float w2 = s * s;                                          \
            const float Qd = fmaf(w2, fmaf(w2, cq2, cq1), cq0);              \
            const float r0 = fmaf(w2, fmaf(w2, NA, NB), NC);                 \
            const float Pn = fmaf(w2, fmaf(w2, cp2, cp1), cp0);              \
            const float uPr = (s * Pn) * r0;                                 \
            const float m1 = Qd * r0;                                        \
            const float A  = fmaf(uPr, (2.f - m1), addA);                    \
            const float fg = dppf<0x00>(A);                                  \
            const float ig = dppf<0x55>(A);                                  \
            const float gu = dppf<0xAA>(A);                                  \
            const float og = dppf<0xFF>(A);                                  \
            c = fmaf(fg, c, ig * gu);                                        \
            const float y  = c * c;                                          \
            const float Q2 = fmaf(y, fmaf(y, (y + 210.f), 4725.f), 10395.f); \
            const float rQ2 = __builtin_amdgcn_rcpf(Q2);                     \
            const float P2 = fmaf(y, fmaf(y, 21.f, 1260.f), 10395.f);        \
            const float ocP = (og * c) * P2;                                 \
            const float kA = ocP * WAc;                                      \
            const float kB = ocP * WBc;                                      \
            zaccA = fmaf(kA, rQ2, (ZN2).x);                                  \
            zaccB = fmaf(kB, rQ2, (ZN2).y);                                  \
            hbufx[hidx] = ocP * rQ2;                                         \
            hidx += hstep;                                                   \
        }

        for (int sbp = 0; sbp < 16; ++sbp) {
            #pragma unroll
            for (int k = 0; k < 16; ++k) zb2[k] = zb2p[ldoff + k * 8];
            #pragma unroll
            for (int k = 0; k < 16; ++k) STEP(za2[k]);
            ldoff += 128;
            #pragma unroll
            for (int k = 0; k < 16; ++k) za2[k] = zb2p[ldoff + k * 8];
            #pragma unroll
            for (int k = 0; k < 16; ++k) STEP(zb2[k]);
            ldoff += 128;
        }
#undef STEP
    }
    __syncthreads();

    // ---- epilogue: out[t] = sigmoid(h[t]*sum(Wc) + bc) (256 threads -> 2 iters) ----
    const float swc = sumWc, b0 = bc[0];
    for (int t = tid; t < Tn; t += 256) {
        out[t] = fsig_hw(fmaf(hbufx[t], swc, b0));
    }
}

extern "C" void kernel_launch(void* const* d_in, const int* in_sizes, int n_in,
                              void* d_out, int out_size, void* d_ws, size_t ws_size,
                              hipStream_t stream) {
    const float* seq = (const float*)d_in[0];
    const float* Wf  = (const float*)d_in[1];
    const float* bf  = (const float*)d_in[2];
    const float* pf  = (const float*)d_in[3];
    const float* Wi  = (const float*)d_in[4];
    const float* bi  = (const float*)d_in[5];
    const float* pi  = (const float*)d_in[6];
    const float* Wu  = (const float*)d_in[7];
    const float* bu  = (const float*)d_in[8];
    const float* pu  = (const float*)d_in[9];
    const float* Wo  = (const float*)d_in[10];
    const float* bo  = (const float*)d_in[11];
    const float* po  = (const float*)d_in[12];
    const float* Wc  = (const float*)d_in[13];
    const float* bc  = (const float*)d_in[14];
    float* out = (float*)d_out;

    fraud_lstm_kernel<<<1, 256, 0, stream>>>(seq, Wf, bf, pf, Wi, bi, pi,
                                             Wu, bu, pu, Wo, bo, po, Wc, bc, out);
}